// Round 1
// baseline (142.446 us; speedup 1.0000x reference)
//
#include <hip/hip_runtime.h>
#include <cstdint>
#include <cstddef>

#define BSTRIDE 98304   // 1024*96 floats per batch

typedef __attribute__((ext_vector_type(8))) short short8;
typedef __attribute__((ext_vector_type(4))) float f32x4;

__device__ __forceinline__ uint16_t f2bf(float x) {
    uint32_t u = __float_as_uint(x);
    return (uint16_t)((u + 0x7FFF + ((u >> 16) & 1)) >> 16);   // RNE
}
__device__ __forceinline__ float bf2f(uint16_t b) {
    return __uint_as_float(((uint32_t)b) << 16);
}

// ---------------------------------------------------------------------------
// Fused kernel, 96 threads/block, 1280 blocks:
//   blocks [0,1024):   one block per s. proj + LN + on-the-fly W + apply,
//                      all intermediates in LDS/regs. Emits Vt[b][i][s] bf16.
//   blocks [1024,1280): Lt[t][s] = bf16(Linker[s][t])  (64x64 tiles, proven)
// ---------------------------------------------------------------------------
union SmemF {
    struct {
        float    xs[8][96];     // x[b][j] for this s          (3072 B)
        float    zs[96][8];     // raw z0 staging, then LN'd Z^T [j][b] (3072 B)
        uint16_t W[96][98];     // W[j][i] bf16, pad 98 -> conflict-free (18816 B)
        float    ps1[8][12];
        float    ps2[8][12];
        float    stats[8][2];
    } f;                        // ~25.2 KB
    struct { float T[64][65]; } kl;
};

__global__ __launch_bounds__(96) void k_fused(
    const float* __restrict__ x, const float* __restrict__ M,
    const float* __restrict__ P, const float* __restrict__ L,
    const float* __restrict__ gamma, const float* __restrict__ beta,
    uint16_t* __restrict__ Lt, uint16_t* __restrict__ Vt)
{
    __shared__ SmemF sm;
    const int t  = threadIdx.x;
    const int bx = blockIdx.x;

    if (bx >= 1024) {
        // ---------------- Linker transpose -> bf16 (unchanged, proven) ----
        const int bx2 = bx - 1024;
        const int s0 = (bx2 & 15) * 64, t0 = (bx2 >> 4) * 64;
        if (t < 64) {
            for (int r = 0; r < 64; ++r)
                sm.kl.T[r][t] = L[(size_t)(s0 + r) * 1024 + t0 + t];
        }
        __syncthreads();
        if (t < 64) {
            uint16_t* orow = Lt + (size_t)(t0 + t) * 1024 + s0;
            #pragma unroll
            for (int c4 = 0; c4 < 16; ++c4) {
                uint32_t u01 = (uint32_t)f2bf(sm.kl.T[c4*4+0][t]) |
                               ((uint32_t)f2bf(sm.kl.T[c4*4+1][t]) << 16);
                uint32_t u23 = (uint32_t)f2bf(sm.kl.T[c4*4+2][t]) |
                               ((uint32_t)f2bf(sm.kl.T[c4*4+3][t]) << 16);
                uint2 o; o.x = u01; o.y = u23;
                *(uint2*)(orow + c4 * 4) = o;
            }
        }
        return;
    }

    const int s = bx;

    // ---- M row of thread's output feature i = t into registers ----
    float mreg[96];
    #pragma unroll
    for (int j0 = 0; j0 < 96; j0 += 4) {
        float4 v = *(const float4*)(M + (size_t)t * 96 + j0);
        mreg[j0+0] = v.x; mreg[j0+1] = v.y; mreg[j0+2] = v.z; mreg[j0+3] = v.w;
    }
    // ---- cooperative x[:,s,:] load (coalesced 384 B per b) ----
    #pragma unroll
    for (int k = 0; k < 8; ++k)
        sm.f.xs[k][t] = x[(size_t)k * BSTRIDE + (size_t)s * 96 + t];
    __syncthreads();

    // ---- proj: zacc[b] = Z0[b,s,t] = sum_j x[b,s,j]*M[t,j] ----
    float zacc[8];
    #pragma unroll
    for (int b = 0; b < 8; ++b) {
        float a0 = 0.f, a1 = 0.f, a2 = 0.f, a3 = 0.f;
        #pragma unroll
        for (int j0 = 0; j0 < 96; j0 += 4) {
            float4 v = *(const float4*)&sm.f.xs[b][j0];
            a0 = fmaf(v.x, mreg[j0+0], a0);
            a1 = fmaf(v.y, mreg[j0+1], a1);
            a2 = fmaf(v.z, mreg[j0+2], a2);
            a3 = fmaf(v.w, mreg[j0+3], a3);
        }
        zacc[b] = (a0 + a1) + (a2 + a3);
    }
    // stage raw z for LN reduction: zs[t][b]
    #pragma unroll
    for (int b = 0; b < 8; ++b) sm.f.zs[t][b] = zacc[b];
    __syncthreads();

    // ---- LN stats: 96 threads = 8 b x 12 groups of 8 rows ----
    {
        const int b = t / 12, grp = t % 12;
        float s1 = 0.f, s2 = 0.f;
        #pragma unroll
        for (int k = 0; k < 8; ++k) {
            float v = sm.f.zs[grp * 8 + k][b];
            s1 += v; s2 += v * v;
        }
        sm.f.ps1[b][grp] = s1; sm.f.ps2[b][grp] = s2;
    }
    __syncthreads();
    if (t < 8) {
        float s1 = 0.f, s2 = 0.f;
        #pragma unroll
        for (int k = 0; k < 12; ++k) { s1 += sm.f.ps1[t][k]; s2 += sm.f.ps2[t][k]; }
        float mu  = s1 * (1.f / 96.f);
        float var = s2 * (1.f / 96.f) - mu * mu;
        sm.f.stats[t][0] = mu;
        sm.f.stats[t][1] = rsqrtf(var + 1e-5f);
    }
    __syncthreads();
    {   // overwrite zs with LN'd Z^T [j][b] (own row, raw reads all done)
        float gm = gamma[t], bt = beta[t];
        #pragma unroll
        for (int b = 0; b < 8; ++b)
            sm.f.zs[t][b] = (zacc[b] - sm.f.stats[b][0]) * sm.f.stats[b][1] * gm + bt;
    }

    // ---- phase A: thread owns j = t; W[j][i] = sum_g P[i,j,g]*cos(2 pi s/per)
    // P loads lane-coalesced: addr = i*3072 + t*32 (+16). per = (i*96+t)*8+g+2.
    {
        const float sf = (float)s;
        const float* Pp = P + (size_t)t * 8;
        float perf = (float)(t * 8 + 2);   // per(i=0, g=0); exact in f32 (<2^23)
        #pragma unroll 2
        for (int i = 0; i < 96; ++i) {
            float4 pa = *(const float4*)(Pp + (size_t)i * 768);
            float4 pb = *(const float4*)(Pp + (size_t)i * 768 + 4);
            float pv[8] = {pa.x, pa.y, pa.z, pa.w, pb.x, pb.y, pb.z, pb.w};
            float w = 0.f;
            #pragma unroll
            for (int g = 0; g < 8; ++g) {
                float inv = __builtin_amdgcn_rcpf(perf + (float)g);
                float a2  = sf * inv;          // revolutions
                a2 -= floorf(a2);              // range-reduce for v_cos
                w = fmaf(pv[g], __builtin_amdgcn_cosf(a2), w);  // cos(2*pi*x)
            }
            sm.f.W[t][i] = f2bf(w);
            perf += 768.0f;
        }
    }
    __syncthreads();

    // ---- phase B: thread owns i = t; T[b] = sum_j Z[b,j]*W[j][t] ----
    float tacc[8] = {0.f,0.f,0.f,0.f,0.f,0.f,0.f,0.f};
    #pragma unroll 4
    for (int j = 0; j < 96; ++j) {
        float w = bf2f(sm.f.W[j][t]);
        float4 z0 = *(const float4*)&sm.f.zs[j][0];
        float4 z1 = *(const float4*)&sm.f.zs[j][4];
        tacc[0] = fmaf(z0.x, w, tacc[0]);
        tacc[1] = fmaf(z0.y, w, tacc[1]);
        tacc[2] = fmaf(z0.z, w, tacc[2]);
        tacc[3] = fmaf(z0.w, w, tacc[3]);
        tacc[4] = fmaf(z1.x, w, tacc[4]);
        tacc[5] = fmaf(z1.y, w, tacc[5]);
        tacc[6] = fmaf(z1.z, w, tacc[6]);
        tacc[7] = fmaf(z1.w, w, tacc[7]);
    }
    // ---- Vt[b][i][s] = bf16(T + Z0) ----
    #pragma unroll
    for (int b = 0; b < 8; ++b)
        Vt[((size_t)b * 96 + t) * 1024 + s] = f2bf(tacc[b] + zacc[b]);
}

// ---------------------------------------------------------------------------
// K3: out[b,t,i] = sum_s Lt[t][s]*Vt[b][i][s]
// Split-K x2: 256 thr = 4 waves; waves {0,1}=K[0,512), {2,3}=K[512,1024),
// tw = wv&1 picks t-subtile. LDS combine. 4 waves/CU (was 2).
// ---------------------------------------------------------------------------
__global__ __launch_bounds__(256) void k3_mfma(
    const uint16_t* __restrict__ Lt, const uint16_t* __restrict__ Vt,
    float* __restrict__ out)
{
    __shared__ float racc[2][64][25];   // pad 25 -> conflict-free
    const int lane = threadIdx.x & 63;
    const int wv   = threadIdx.x >> 6;
    const int tw   = wv & 1;
    const int kw   = wv >> 1;
    const int m    = lane & 15;
    const int quad = lane >> 4;
    const int t0   = blockIdx.x * 32 + tw * 16;
    const int b    = blockIdx.y;

    const uint16_t* Lp = Lt + (size_t)(t0 + m) * 1024 + kw * 512 + quad * 8;
    const uint16_t* Vp = Vt + ((size_t)b * 96 + m) * 1024 + kw * 512 + quad * 8;

    f32x4 acc[6];
    #pragma unroll
    for (int ii = 0; ii < 6; ++ii) acc[ii] = (f32x4){0.f, 0.f, 0.f, 0.f};

    short8 a = *(const short8*)Lp;
    short8 bv[6];
    #pragma unroll
    for (int ii = 0; ii < 6; ++ii)
        bv[ii] = *(const short8*)(Vp + (size_t)ii * 16 * 1024);

    for (int kc = 0; kc < 15; ++kc) {
        short8 an = *(const short8*)(Lp + (kc + 1) * 32);
        short8 bn[6];
        #pragma unroll
        for (int ii = 0; ii < 6; ++ii)
            bn[ii] = *(const short8*)(Vp + (size_t)ii * 16 * 1024 + (kc + 1) * 32);
        #pragma unroll
        for (int ii = 0; ii < 6; ++ii)
            acc[ii] = __builtin_amdgcn_mfma_f32_16x16x32_bf16(a, bv[ii], acc[ii], 0, 0, 0);
        a = an;
        #pragma unroll
        for (int ii = 0; ii < 6; ++ii) bv[ii] = bn[ii];
    }
    #pragma unroll
    for (int ii = 0; ii < 6; ++ii)
        acc[ii] = __builtin_amdgcn_mfma_f32_16x16x32_bf16(a, bv[ii], acc[ii], 0, 0, 0);

    if (kw == 1) {
        #pragma unroll
        for (int ii = 0; ii < 6; ++ii)
            #pragma unroll
            for (int r = 0; r < 4; ++r)
                racc[tw][lane][ii * 4 + r] = acc[ii][r];
    }
    __syncthreads();
    if (kw == 0) {
        float* po = out + (size_t)b * BSTRIDE;
        #pragma unroll
        for (int ii = 0; ii < 6; ++ii)
            #pragma unroll
            for (int r = 0; r < 4; ++r)
                po[(size_t)(t0 + quad * 4 + r) * 96 + ii * 16 + m] =
                    acc[ii][r] + racc[tw][lane][ii * 4 + r];
    }
}

extern "C" void kernel_launch(void* const* d_in, const int* in_sizes, int n_in,
                              void* d_out, int out_size, void* d_ws, size_t ws_size,
                              hipStream_t stream)
{
    const float* x     = (const float*)d_in[0];
    const float* M     = (const float*)d_in[1];
    const float* P     = (const float*)d_in[2];
    const float* Lnk   = (const float*)d_in[3];
    const float* gamma = (const float*)d_in[4];
    const float* beta  = (const float*)d_in[5];
    float* out = (float*)d_out;

    uint8_t* ws = (uint8_t*)d_ws;
    uint16_t* Lt = (uint16_t*)ws;                 // 2,097,152 B
    uint16_t* Vt = (uint16_t*)(ws + 2097152);     // 1,572,864 B

    k_fused <<<1280, 96, 0, stream>>>(x, M, P, Lnk, gamma, beta, Lt, Vt);
    k3_mfma <<<dim3(32, 8), 256, 0, stream>>>(Lt, Vt, out);
}

// Round 2
// 124.615 us; speedup vs baseline: 1.1431x; 1.1431x over previous
//
#include <hip/hip_runtime.h>
#include <cstdint>
#include <cstddef>

#define BSTRIDE 98304   // 1024*96 floats per batch

typedef __attribute__((ext_vector_type(8))) short short8;
typedef __attribute__((ext_vector_type(4))) float f32x4;

__device__ __forceinline__ uint16_t f2bf(float x) {
    uint32_t u = __float_as_uint(x);
    return (uint16_t)((u + 0x7FFF + ((u >> 16) & 1)) >> 16);   // RNE
}
__device__ __forceinline__ float bf2f(uint16_t b) {
    return __uint_as_float(((uint32_t)b) << 16);
}

// ---------------------------------------------------------------------------
// Fused kernel, 384 threads/block (6 waves):
//   blocks [0,1024):   one block per s. proj + LN + on-the-fly W + apply.
//     Thread = (e = t%96, q = t/96).  4-way work split per phase:
//       proj:    (i=e, jq=q)  partial dot over 24 j, LDS combine
//       phase A: (j=e, iq=q)  W[j][i] for i in q-quarter (coalesced P loads)
//       phase B: (i=e, jq=q)  partial T over 24 j, LDS combine
//     Emits Vt[b][i][s] bf16.  No Z/Z0/W in HBM.
//   blocks [1024,1280): Lt[t][s] = bf16(Linker[s][t]) (64x64 tiles, proven)
// ---------------------------------------------------------------------------
struct SmemS {
    union { float xs[8][96]; float zr[96][8]; } u;  // 3072 B (xs: proj, zr: after)
    float zs[96][8];                                // 3072 B  LN'd Z^T [j][b]
    float part[4][8][96];                           // 12288 B partial sums
    uint16_t W[96][100];                            // 19200 B (row 200 B, 4-aligned)
    float ps1[8][12], ps2[8][12], stats[8][2];      // 832 B
};
union SmemF { SmemS f; struct { float T[64][65]; } kl; };   // ~38.5 KB

__global__ __launch_bounds__(384, 5) void k_fused(
    const float* __restrict__ x, const float* __restrict__ M,
    const float* __restrict__ P, const float* __restrict__ L,
    const float* __restrict__ gamma, const float* __restrict__ beta,
    uint16_t* __restrict__ Lt, uint16_t* __restrict__ Vt)
{
    __shared__ SmemF sm;
    const int t  = threadIdx.x;
    const int bx = blockIdx.x;

    if (bx >= 1024) {
        // ---------------- Linker transpose -> bf16 (proven) ----------------
        const int bx2 = bx - 1024;
        const int s0 = (bx2 & 15) * 64, t0 = (bx2 >> 4) * 64;
        if (t < 64) {
            for (int r = 0; r < 64; ++r)
                sm.kl.T[r][t] = L[(size_t)(s0 + r) * 1024 + t0 + t];
        }
        __syncthreads();
        if (t < 64) {
            uint16_t* orow = Lt + (size_t)(t0 + t) * 1024 + s0;
            #pragma unroll
            for (int c4 = 0; c4 < 16; ++c4) {
                uint32_t u01 = (uint32_t)f2bf(sm.kl.T[c4*4+0][t]) |
                               ((uint32_t)f2bf(sm.kl.T[c4*4+1][t]) << 16);
                uint32_t u23 = (uint32_t)f2bf(sm.kl.T[c4*4+2][t]) |
                               ((uint32_t)f2bf(sm.kl.T[c4*4+3][t]) << 16);
                uint2 o; o.x = u01; o.y = u23;
                *(uint2*)(orow + c4 * 4) = o;
            }
        }
        return;
    }

    const int s = bx;
    const int e = t % 96;          // lane within 96-group
    const int q = t / 96;          // quarter 0..3
    const int jq = q * 24;

    // ---- cooperative x[:,s,:] load: 768 f32, 2 per thread, coalesced ----
    {
        float* xf = &sm.f.u.xs[0][0];
        #pragma unroll
        for (int r = 0; r < 2; ++r) {
            int idx = t + r * 384;
            int b = idx / 96, j = idx - b * 96;
            xf[idx] = x[(size_t)b * BSTRIDE + (size_t)s * 96 + j];
        }
    }
    __syncthreads();

    // ---- proj partial: thread (i=e, q): 24-j dot for 8 b ----
    {
        float acc[8] = {0.f,0.f,0.f,0.f,0.f,0.f,0.f,0.f};
        const float* Mp = M + (size_t)e * 96 + jq;
        #pragma unroll
        for (int jj4 = 0; jj4 < 6; ++jj4) {
            float4 m4 = *(const float4*)(Mp + jj4 * 4);
            #pragma unroll
            for (int b = 0; b < 8; ++b) {
                float4 xv = *(const float4*)&sm.f.u.xs[b][jq + jj4 * 4];
                acc[b] = fmaf(m4.x, xv.x,
                         fmaf(m4.y, xv.y,
                         fmaf(m4.z, xv.z,
                         fmaf(m4.w, xv.w, acc[b]))));
            }
        }
        #pragma unroll
        for (int b = 0; b < 8; ++b) sm.f.part[q][b][e] = acc[b];
    }
    __syncthreads();

    // ---- combine partials -> zr[i][b] (raw Z0 row s) ----
    {
        #pragma unroll
        for (int bb = 0; bb < 2; ++bb) {
            int b = q * 2 + bb;
            float v = sm.f.part[0][b][e] + sm.f.part[1][b][e] +
                      sm.f.part[2][b][e] + sm.f.part[3][b][e];
            sm.f.u.zr[e][b] = v;
        }
    }
    __syncthreads();

    // ---- LN stats ----
    if (t < 96) {
        const int b = t / 12, grp = t % 12;
        float s1 = 0.f, s2 = 0.f;
        #pragma unroll
        for (int k = 0; k < 8; ++k) {
            float v = sm.f.u.zr[grp * 8 + k][b];
            s1 += v; s2 += v * v;
        }
        sm.f.ps1[b][grp] = s1; sm.f.ps2[b][grp] = s2;
    }
    __syncthreads();
    if (t < 8) {
        float s1 = 0.f, s2 = 0.f;
        #pragma unroll
        for (int k = 0; k < 12; ++k) { s1 += sm.f.ps1[t][k]; s2 += sm.f.ps2[t][k]; }
        float mu  = s1 * (1.f / 96.f);
        float var = s2 * (1.f / 96.f) - mu * mu;
        sm.f.stats[t][0] = mu;
        sm.f.stats[t][1] = rsqrtf(var + 1e-5f);
    }
    __syncthreads();

    // ---- zs[j][b] = LN'd Z^T ----
    {
        float gm = gamma[e], bt = beta[e];
        #pragma unroll
        for (int bb = 0; bb < 2; ++bb) {
            int b = q * 2 + bb;
            sm.f.zs[e][b] =
                (sm.f.u.zr[e][b] - sm.f.stats[b][0]) * sm.f.stats[b][1] * gm + bt;
        }
    }

    // ---- phase A: thread (j=e, iq=q): W[j][i] for 24 i, 2 at a time ----
    // P loads lane-coalesced: P[(i*96+j)*8+g], lanes j consecutive = 32B/lane.
    {
        const float sf = (float)s;
        const int j = e;
        #pragma unroll 1
        for (int ii = 0; ii < 24; ii += 2) {
            const int i0 = q * 24 + ii;              // even
            const float* Pp = P + ((size_t)i0 * 96 + j) * 8;
            float4 pa = *(const float4*)(Pp);
            float4 pb = *(const float4*)(Pp + 4);
            float4 pc = *(const float4*)(Pp + 768);
            float4 pd = *(const float4*)(Pp + 772);
            float pv0[8] = {pa.x, pa.y, pa.z, pa.w, pb.x, pb.y, pb.z, pb.w};
            float pv1[8] = {pc.x, pc.y, pc.z, pc.w, pd.x, pd.y, pd.z, pd.w};
            float base0 = (float)((i0 * 96 + j) * 8 + 2);
            float base1 = base0 + 768.0f;
            float w0 = 0.f, w1 = 0.f;
            #pragma unroll
            for (int g = 0; g < 8; ++g) {
                float inv0 = __builtin_amdgcn_rcpf(base0 + (float)g);
                float inv1 = __builtin_amdgcn_rcpf(base1 + (float)g);
                float a0 = sf * inv0; a0 -= floorf(a0);
                float a1 = sf * inv1; a1 -= floorf(a1);
                w0 = fmaf(pv0[g], __builtin_amdgcn_cosf(a0), w0);
                w1 = fmaf(pv1[g], __builtin_amdgcn_cosf(a1), w1);
            }
            *(uint32_t*)&sm.f.W[j][i0] =
                (uint32_t)f2bf(w0) | ((uint32_t)f2bf(w1) << 16);
        }
    }
    __syncthreads();

    // ---- phase B: thread (i=e, jq=q): partial T over 24 j for 8 b ----
    {
        float tacc[8] = {0.f,0.f,0.f,0.f,0.f,0.f,0.f,0.f};
        #pragma unroll 4
        for (int jj = 0; jj < 24; ++jj) {
            int j = jq + jj;
            float w = bf2f(sm.f.W[j][e]);
            float4 z0 = *(const float4*)&sm.f.zs[j][0];
            float4 z1 = *(const float4*)&sm.f.zs[j][4];
            tacc[0] = fmaf(z0.x, w, tacc[0]);
            tacc[1] = fmaf(z0.y, w, tacc[1]);
            tacc[2] = fmaf(z0.z, w, tacc[2]);
            tacc[3] = fmaf(z0.w, w, tacc[3]);
            tacc[4] = fmaf(z1.x, w, tacc[4]);
            tacc[5] = fmaf(z1.y, w, tacc[5]);
            tacc[6] = fmaf(z1.z, w, tacc[6]);
            tacc[7] = fmaf(z1.w, w, tacc[7]);
        }
        #pragma unroll
        for (int b = 0; b < 8; ++b) sm.f.part[q][b][e] = tacc[b];
    }
    __syncthreads();

    // ---- final: combine + residual + Vt write ----
    {
        #pragma unroll
        for (int bb = 0; bb < 2; ++bb) {
            int b = q * 2 + bb;
            float T = sm.f.part[0][b][e] + sm.f.part[1][b][e] +
                      sm.f.part[2][b][e] + sm.f.part[3][b][e];
            float z0 = sm.f.u.zr[e][b];
            Vt[((size_t)b * 96 + e) * 1024 + s] = f2bf(T + z0);
        }
    }
}

// ---------------------------------------------------------------------------
// K3: out[b,t,i] = sum_s Lt[t][s]*Vt[b][i][s]
// Split-K x4: 256 thr = 4 waves, each K=256 (8 MFMA k-chunks), t-tile 16.
// grid (64,8) = 512 blocks -> 2048 waves = 8 waves/CU.  LDS combine.
// ---------------------------------------------------------------------------
__global__ __launch_bounds__(256) void k3_mfma(
    const uint16_t* __restrict__ Lt, const uint16_t* __restrict__ Vt,
    float* __restrict__ out)
{
    __shared__ float racc[3][64][25];   // pad 25 -> conflict-free
    const int lane = threadIdx.x & 63;
    const int kw   = threadIdx.x >> 6;      // 0..3
    const int m    = lane & 15;
    const int quad = lane >> 4;
    const int t0   = blockIdx.x * 16;
    const int b    = blockIdx.y;

    const uint16_t* Lp = Lt + (size_t)(t0 + m) * 1024 + kw * 256 + quad * 8;
    const uint16_t* Vp = Vt + ((size_t)b * 96 + m) * 1024 + kw * 256 + quad * 8;

    f32x4 acc[6];
    #pragma unroll
    for (int ii = 0; ii < 6; ++ii) acc[ii] = (f32x4){0.f, 0.f, 0.f, 0.f};

    short8 a = *(const short8*)Lp;
    short8 bv[6];
    #pragma unroll
    for (int ii = 0; ii < 6; ++ii)
        bv[ii] = *(const short8*)(Vp + (size_t)ii * 16 * 1024);

    for (int kc = 0; kc < 7; ++kc) {
        short8 an = *(const short8*)(Lp + (kc + 1) * 32);
        short8 bn[6];
        #pragma unroll
        for (int ii = 0; ii < 6; ++ii)
            bn[ii] = *(const short8*)(Vp + (size_t)ii * 16 * 1024 + (kc + 1) * 32);
        #pragma unroll
        for (int ii = 0; ii < 6; ++ii)
            acc[ii] = __builtin_amdgcn_mfma_f32_16x16x32_bf16(a, bv[ii], acc[ii], 0, 0, 0);
        a = an;
        #pragma unroll
        for (int ii = 0; ii < 6; ++ii) bv[ii] = bn[ii];
    }
    #pragma unroll
    for (int ii = 0; ii < 6; ++ii)
        acc[ii] = __builtin_amdgcn_mfma_f32_16x16x32_bf16(a, bv[ii], acc[ii], 0, 0, 0);

    if (kw > 0) {
        #pragma unroll
        for (int ii = 0; ii < 6; ++ii)
            #pragma unroll
            for (int r = 0; r < 4; ++r)
                racc[kw - 1][lane][ii * 4 + r] = acc[ii][r];
    }
    __syncthreads();
    if (kw == 0) {
        float* po = out + (size_t)b * BSTRIDE;
        #pragma unroll
        for (int ii = 0; ii < 6; ++ii)
            #pragma unroll
            for (int r = 0; r < 4; ++r)
                po[(size_t)(t0 + quad * 4 + r) * 96 + ii * 16 + m] =
                    acc[ii][r] + racc[0][lane][ii * 4 + r] +
                    racc[1][lane][ii * 4 + r] + racc[2][lane][ii * 4 + r];
    }
}

extern "C" void kernel_launch(void* const* d_in, const int* in_sizes, int n_in,
                              void* d_out, int out_size, void* d_ws, size_t ws_size,
                              hipStream_t stream)
{
    const float* x     = (const float*)d_in[0];
    const float* M     = (const float*)d_in[1];
    const float* P     = (const float*)d_in[2];
    const float* Lnk   = (const float*)d_in[3];
    const float* gamma = (const float*)d_in[4];
    const float* beta  = (const float*)d_in[5];
    float* out = (float*)d_out;

    uint8_t* ws = (uint8_t*)d_ws;
    uint16_t* Lt = (uint16_t*)ws;                 // 2,097,152 B
    uint16_t* Vt = (uint16_t*)(ws + 2097152);     // 1,572,864 B

    k_fused <<<1280, 384, 0, stream>>>(x, M, P, Lnk, gamma, beta, Lt, Vt);
    k3_mfma <<<dim3(64, 8), 256, 0, stream>>>(Lt, Vt, out);
}

// Round 3
// 115.487 us; speedup vs baseline: 1.2334x; 1.0790x over previous
//
#include <hip/hip_runtime.h>
#include <cstdint>
#include <cstddef>

#define BSTRIDE 98304   // 1024*96 floats per batch

typedef __attribute__((ext_vector_type(8))) short short8;
typedef __attribute__((ext_vector_type(4))) float f32x4;

__device__ __forceinline__ uint16_t f2bf(float x) {
    uint32_t u = __float_as_uint(x);
    return (uint16_t)((u + 0x7FFF + ((u >> 16) & 1)) >> 16);   // RNE
}
__device__ __forceinline__ float bf2f(uint16_t b) {
    return __uint_as_float(((uint32_t)b) << 16);
}

// ---------------------------------------------------------------------------
// Fused kernel, 384 threads/block (6 waves):
//   blocks [0,1024):   one block per s. proj + LN + on-the-fly W + apply.
//     LDS cut to ~26 KB by aliasing part[] onto W[] (never both live):
//       proj partial -> part | combine reads part -> zr | (part dead)
//       phase A writes W | phase B reads W into regs | barrier | (W dead)
//       part rewritten | combine -> Vt
//   blocks [1024,1280): Lt[t][s] = bf16(Linker[s][t]) (64x64 tiles, proven)
// ---------------------------------------------------------------------------
struct SmemS {
    union { float xs[8][96]; float zr[96][8]; } u;       // 3072 B
    float zs[96][8];                                      // 3072 B
    union { uint16_t W[96][100]; float part[4][8][96]; } w; // 19200 B
    float ps1[8][12], ps2[8][12], stats[8][2];            // 832 B
};
union SmemF { SmemS f; struct { float T[64][65]; } kl; };  // ~26.2 KB

__global__ __launch_bounds__(384, 7) void k_fused(
    const float* __restrict__ x, const float* __restrict__ M,
    const float* __restrict__ P, const float* __restrict__ L,
    const float* __restrict__ gamma, const float* __restrict__ beta,
    uint16_t* __restrict__ Lt, uint16_t* __restrict__ Vt)
{
    __shared__ SmemF sm;
    const int t  = threadIdx.x;
    const int bx = blockIdx.x;

    if (bx >= 1024) {
        // ---------------- Linker transpose -> bf16 (proven) ----------------
        const int bx2 = bx - 1024;
        const int s0 = (bx2 & 15) * 64, t0 = (bx2 >> 4) * 64;
        if (t < 64) {
            for (int r = 0; r < 64; ++r)
                sm.kl.T[r][t] = L[(size_t)(s0 + r) * 1024 + t0 + t];
        }
        __syncthreads();
        if (t < 64) {
            uint16_t* orow = Lt + (size_t)(t0 + t) * 1024 + s0;
            #pragma unroll
            for (int c4 = 0; c4 < 16; ++c4) {
                uint32_t u01 = (uint32_t)f2bf(sm.kl.T[c4*4+0][t]) |
                               ((uint32_t)f2bf(sm.kl.T[c4*4+1][t]) << 16);
                uint32_t u23 = (uint32_t)f2bf(sm.kl.T[c4*4+2][t]) |
                               ((uint32_t)f2bf(sm.kl.T[c4*4+3][t]) << 16);
                uint2 o; o.x = u01; o.y = u23;
                *(uint2*)(orow + c4 * 4) = o;
            }
        }
        return;
    }

    const int s = bx;
    const int e = t % 96;          // lane within 96-group
    const int q = t / 96;          // quarter 0..3
    const int jq = q * 24;

    // ---- cooperative x[:,s,:] load: 768 f32, 2 per thread, coalesced ----
    {
        float* xf = &sm.f.u.xs[0][0];
        #pragma unroll
        for (int r = 0; r < 2; ++r) {
            int idx = t + r * 384;
            int b = idx / 96, j = idx - b * 96;
            xf[idx] = x[(size_t)b * BSTRIDE + (size_t)s * 96 + j];
        }
    }
    __syncthreads();

    // ---- proj partial: thread (i=e, q): 24-j dot for 8 b ----
    {
        float acc[8] = {0.f,0.f,0.f,0.f,0.f,0.f,0.f,0.f};
        const float* Mp = M + (size_t)e * 96 + jq;
        #pragma unroll
        for (int jj4 = 0; jj4 < 6; ++jj4) {
            float4 m4 = *(const float4*)(Mp + jj4 * 4);
            #pragma unroll
            for (int b = 0; b < 8; ++b) {
                float4 xv = *(const float4*)&sm.f.u.xs[b][jq + jj4 * 4];
                acc[b] = fmaf(m4.x, xv.x,
                         fmaf(m4.y, xv.y,
                         fmaf(m4.z, xv.z,
                         fmaf(m4.w, xv.w, acc[b]))));
            }
        }
        #pragma unroll
        for (int b = 0; b < 8; ++b) sm.f.w.part[q][b][e] = acc[b];
    }
    __syncthreads();

    // ---- combine partials -> zr[i][b] (raw Z0 row s); part dead after ----
    {
        #pragma unroll
        for (int bb = 0; bb < 2; ++bb) {
            int b = q * 2 + bb;
            float v = sm.f.w.part[0][b][e] + sm.f.w.part[1][b][e] +
                      sm.f.w.part[2][b][e] + sm.f.w.part[3][b][e];
            sm.f.u.zr[e][b] = v;
        }
    }
    __syncthreads();

    // ---- LN stats ----
    if (t < 96) {
        const int b = t / 12, grp = t % 12;
        float s1 = 0.f, s2 = 0.f;
        #pragma unroll
        for (int k = 0; k < 8; ++k) {
            float v = sm.f.u.zr[grp * 8 + k][b];
            s1 += v; s2 += v * v;
        }
        sm.f.ps1[b][grp] = s1; sm.f.ps2[b][grp] = s2;
    }
    __syncthreads();
    if (t < 8) {
        float s1 = 0.f, s2 = 0.f;
        #pragma unroll
        for (int k = 0; k < 12; ++k) { s1 += sm.f.ps1[t][k]; s2 += sm.f.ps2[t][k]; }
        float mu  = s1 * (1.f / 96.f);
        float var = s2 * (1.f / 96.f) - mu * mu;
        sm.f.stats[t][0] = mu;
        sm.f.stats[t][1] = rsqrtf(var + 1e-5f);
    }
    __syncthreads();

    // ---- zs[j][b] = LN'd Z^T ----
    {
        float gm = gamma[e], bt = beta[e];
        #pragma unroll
        for (int bb = 0; bb < 2; ++bb) {
            int b = q * 2 + bb;
            sm.f.zs[e][b] =
                (sm.f.u.zr[e][b] - sm.f.stats[b][0]) * sm.f.stats[b][1] * gm + bt;
        }
    }

    // ---- phase A: thread (j=e, iq=q): W[j][i] for 24 i, 2 at a time ----
    // P loads lane-coalesced (32 B/lane contiguous). Pointer-bump addressing.
    {
        const float sf = (float)s;
        const int j = e;
        const float* Pp = P + ((size_t)jq * 96 + j) * 8;
        float base0 = (float)((jq * 96 + j) * 8 + 2);
        uint16_t* wrow = &sm.f.w.W[j][jq];
        #pragma unroll 2
        for (int ii = 0; ii < 24; ii += 2) {
            float4 pa = *(const float4*)(Pp);
            float4 pb = *(const float4*)(Pp + 4);
            float4 pc = *(const float4*)(Pp + 768);
            float4 pd = *(const float4*)(Pp + 772);
            float pv0[8] = {pa.x, pa.y, pa.z, pa.w, pb.x, pb.y, pb.z, pb.w};
            float pv1[8] = {pc.x, pc.y, pc.z, pc.w, pd.x, pd.y, pd.z, pd.w};
            float w0 = 0.f, w1 = 0.f;
            #pragma unroll
            for (int g = 0; g < 8; ++g) {
                float inv0 = __builtin_amdgcn_rcpf(base0 + (float)g);
                float inv1 = __builtin_amdgcn_rcpf(base0 + (float)(768 + g));
                float a0 = __builtin_amdgcn_fractf(sf * inv0);
                float a1 = __builtin_amdgcn_fractf(sf * inv1);
                w0 = fmaf(pv0[g], __builtin_amdgcn_cosf(a0), w0);
                w1 = fmaf(pv1[g], __builtin_amdgcn_cosf(a1), w1);
            }
            *(uint32_t*)(wrow + ii) =
                (uint32_t)f2bf(w0) | ((uint32_t)f2bf(w1) << 16);
            Pp += 1536; base0 += 1536.0f;
        }
    }
    __syncthreads();

    // ---- phase B: thread (i=e, jq=q): partial T over 24 j, into regs ----
    float tacc[8] = {0.f,0.f,0.f,0.f,0.f,0.f,0.f,0.f};
    {
        #pragma unroll 4
        for (int jj = 0; jj < 24; ++jj) {
            int j = jq + jj;
            float w = bf2f(sm.f.w.W[j][e]);
            float4 z0 = *(const float4*)&sm.f.zs[j][0];
            float4 z1 = *(const float4*)&sm.f.zs[j][4];
            tacc[0] = fmaf(z0.x, w, tacc[0]);
            tacc[1] = fmaf(z0.y, w, tacc[1]);
            tacc[2] = fmaf(z0.z, w, tacc[2]);
            tacc[3] = fmaf(z0.w, w, tacc[3]);
            tacc[4] = fmaf(z1.x, w, tacc[4]);
            tacc[5] = fmaf(z1.y, w, tacc[5]);
            tacc[6] = fmaf(z1.z, w, tacc[6]);
            tacc[7] = fmaf(z1.w, w, tacc[7]);
        }
    }
    __syncthreads();           // all W reads complete; W dead, part reusable
    {
        #pragma unroll
        for (int b = 0; b < 8; ++b) sm.f.w.part[q][b][e] = tacc[b];
    }
    __syncthreads();

    // ---- final: combine + residual + Vt write ----
    {
        #pragma unroll
        for (int bb = 0; bb < 2; ++bb) {
            int b = q * 2 + bb;
            float T = sm.f.w.part[0][b][e] + sm.f.w.part[1][b][e] +
                      sm.f.w.part[2][b][e] + sm.f.w.part[3][b][e];
            float z0 = sm.f.u.zr[e][b];
            Vt[((size_t)b * 96 + e) * 1024 + s] = f2bf(T + z0);
        }
    }
}

// ---------------------------------------------------------------------------
// K3: out[b,t,i] = sum_s Lt[t][s]*Vt[b][i][s]
// Split-K x8: 512 thr = 8 waves, each K=128 (4 MFMA k-chunks), t-tile 16.
// ALL 28 operand loads prefetched up-front (independent -> one latency
// exposure), then 24 MFMAs, then parallel 8-wave LDS combine.
// grid (64,8) = 512 blocks.
// ---------------------------------------------------------------------------
__global__ __launch_bounds__(512, 2) void k3_mfma(
    const uint16_t* __restrict__ Lt, const uint16_t* __restrict__ Vt,
    float* __restrict__ out)
{
    __shared__ float racc[8][64][25];   // 51200 B, pad 25 -> conflict-free
    const int lane = threadIdx.x & 63;
    const int kw   = threadIdx.x >> 6;      // 0..7
    const int m    = lane & 15;
    const int quad = lane >> 4;
    const int t0   = blockIdx.x * 16;
    const int b    = blockIdx.y;

    const uint16_t* Lp = Lt + (size_t)(t0 + m) * 1024 + kw * 128 + quad * 8;
    const uint16_t* Vp = Vt + ((size_t)b * 96 + m) * 1024 + kw * 128 + quad * 8;

    short8 a[4];
    short8 bv[4][6];
    #pragma unroll
    for (int kc = 0; kc < 4; ++kc) {
        a[kc] = *(const short8*)(Lp + kc * 32);
        #pragma unroll
        for (int ii = 0; ii < 6; ++ii)
            bv[kc][ii] = *(const short8*)(Vp + (size_t)ii * 16 * 1024 + kc * 32);
    }

    f32x4 acc[6];
    #pragma unroll
    for (int ii = 0; ii < 6; ++ii) acc[ii] = (f32x4){0.f, 0.f, 0.f, 0.f};
    #pragma unroll
    for (int kc = 0; kc < 4; ++kc)
        #pragma unroll
        for (int ii = 0; ii < 6; ++ii)
            acc[ii] = __builtin_amdgcn_mfma_f32_16x16x32_bf16(a[kc], bv[kc][ii], acc[ii], 0, 0, 0);

    #pragma unroll
    for (int ii = 0; ii < 6; ++ii)
        #pragma unroll
        for (int r = 0; r < 4; ++r)
            racc[kw][lane][ii * 4 + r] = acc[ii][r];
    __syncthreads();

    // parallel combine: wave kw owns slots [3kw, 3kw+3)
    float* po = out + (size_t)b * BSTRIDE;
    #pragma unroll
    for (int sl = 0; sl < 3; ++sl) {
        int slot = kw * 3 + sl;
        int ii = slot >> 2, r = slot & 3;
        float v = 0.f;
        #pragma unroll
        for (int k = 0; k < 8; ++k) v += racc[k][lane][slot];
        po[(size_t)(t0 + quad * 4 + r) * 96 + ii * 16 + m] = v;
    }
}

extern "C" void kernel_launch(void* const* d_in, const int* in_sizes, int n_in,
                              void* d_out, int out_size, void* d_ws, size_t ws_size,
                              hipStream_t stream)
{
    const float* x     = (const float*)d_in[0];
    const float* M     = (const float*)d_in[1];
    const float* P     = (const float*)d_in[2];
    const float* Lnk   = (const float*)d_in[3];
    const float* gamma = (const float*)d_in[4];
    const float* beta  = (const float*)d_in[5];
    float* out = (float*)d_out;

    uint8_t* ws = (uint8_t*)d_ws;
    uint16_t* Lt = (uint16_t*)ws;                 // 2,097,152 B
    uint16_t* Vt = (uint16_t*)(ws + 2097152);     // 1,572,864 B

    k_fused <<<1280, 384, 0, stream>>>(x, M, P, Lnk, gamma, beta, Lt, Vt);
    k3_mfma <<<dim3(64, 8), 512, 0, stream>>>(Lt, Vt, out);
}

// Round 4
// 112.066 us; speedup vs baseline: 1.2711x; 1.0305x over previous
//
#include <hip/hip_runtime.h>
#include <cstdint>
#include <cstddef>

#define BSTRIDE 98304   // 1024*96 floats per batch

typedef __attribute__((ext_vector_type(8))) short short8;
typedef __attribute__((ext_vector_type(4))) float f32x4;

__device__ __forceinline__ uint16_t f2bf(float x) {
    uint32_t u = __float_as_uint(x);
    return (uint16_t)((u + 0x7FFF + ((u >> 16) & 1)) >> 16);   // RNE
}
__device__ __forceinline__ float bf2f(uint16_t b) {
    return __uint_as_float(((uint32_t)b) << 16);
}
__device__ __forceinline__ float cosrev(float x) {   // cos(2*pi*x), x in revs
    return __builtin_amdgcn_cosf(x);
}

// ---------------------------------------------------------------------------
// kA: proj + LN (+ Linker transpose).  384 thr.
//   blocks [0,512):   16 global rows (b,s) each: Z0/Z in layout [s][b][i] f32
//   blocks [512,768): Lt[t][s] = bf16(Linker[s][t])  (64x64 tiles, proven)
// ---------------------------------------------------------------------------
union SmemA {
    struct {
        union {
            float M[96][97];                         // 37248 B
            struct { float zb[16][97]; float ps1[16][8];
                     float ps2[16][8]; float stats[16][2]; } ln;
        } m;
        float xs[16][96];                            // 6144 B
    } a;                                             // ~43.4 KB
    struct { float T[64][65]; } kl;
};

__global__ __launch_bounds__(384, 4) void kA(
    const float* __restrict__ x, const float* __restrict__ M,
    const float* __restrict__ L,
    const float* __restrict__ gamma, const float* __restrict__ beta,
    float* __restrict__ Z0, float* __restrict__ Z, uint16_t* __restrict__ Lt)
{
    __shared__ SmemA sm;
    const int t  = threadIdx.x;
    const int bx = blockIdx.x;

    if (bx >= 512) {
        // ---------------- Linker transpose -> bf16 (proven; t<64 active) ---
        const int bx2 = bx - 512;
        const int s0 = (bx2 & 15) * 64, t0 = (bx2 >> 4) * 64;
        if (t < 64) {
            for (int r = 0; r < 64; ++r)
                sm.kl.T[r][t] = L[(size_t)(s0 + r) * 1024 + t0 + t];
        }
        __syncthreads();
        if (t < 64) {
            uint16_t* orow = Lt + (size_t)(t0 + t) * 1024 + s0;
            #pragma unroll
            for (int c4 = 0; c4 < 16; ++c4) {
                uint32_t u01 = (uint32_t)f2bf(sm.kl.T[c4*4+0][t]) |
                               ((uint32_t)f2bf(sm.kl.T[c4*4+1][t]) << 16);
                uint32_t u23 = (uint32_t)f2bf(sm.kl.T[c4*4+2][t]) |
                               ((uint32_t)f2bf(sm.kl.T[c4*4+3][t]) << 16);
                uint2 o; o.x = u01; o.y = u23;
                *(uint2*)(orow + c4 * 4) = o;
            }
        }
        return;
    }

    const int R0 = bx * 16;               // 16 rows, all same b (16 | 1024)
    const int b  = R0 >> 10;
    const int sb = R0 & 1023;

    // ---- stage M (96x96) into LDS, padded row 97 ----
    #pragma unroll
    for (int k = 0; k < 6; ++k) {
        int mm = t + 384 * k;
        int i = mm / 24, j0 = (mm % 24) * 4;
        float4 v = *(const float4*)(M + (size_t)i * 96 + j0);
        sm.a.m.M[i][j0]   = v.x; sm.a.m.M[i][j0+1] = v.y;
        sm.a.m.M[i][j0+2] = v.z; sm.a.m.M[i][j0+3] = v.w;
    }
    // ---- stage x rows ----
    {
        int row = t / 24, j0 = (t % 24) * 4;
        float4 v = *(const float4*)(x + (size_t)(R0 + row) * 96 + j0);
        *(float4*)&sm.a.xs[row][j0] = v;
    }
    __syncthreads();

    const int e = t % 96;     // feature i
    const int q = t / 96;     // row quarter: rows q*4 .. q*4+3
    float acc[4] = {0.f, 0.f, 0.f, 0.f};
    for (int j0 = 0; j0 < 96; j0 += 4) {
        float m0 = sm.a.m.M[e][j0+0], m1 = sm.a.m.M[e][j0+1];
        float m2 = sm.a.m.M[e][j0+2], m3 = sm.a.m.M[e][j0+3];
        #pragma unroll
        for (int rr = 0; rr < 4; ++rr) {
            float4 xv = *(const float4*)&sm.a.xs[q * 4 + rr][j0];
            acc[rr] = fmaf(m0, xv.x, fmaf(m1, xv.y,
                      fmaf(m2, xv.z, fmaf(m3, xv.w, acc[rr]))));
        }
    }
    __syncthreads();          // all M reads done; ln region aliases M
    #pragma unroll
    for (int rr = 0; rr < 4; ++rr) sm.a.m.ln.zb[q * 4 + rr][e] = acc[rr];
    __syncthreads();

    if (t < 128) {            // 16 rows x 8 segments of 12
        int r = t >> 3, seg = t & 7;
        float s1 = 0.f, s2 = 0.f;
        #pragma unroll
        for (int k = 0; k < 12; ++k) {
            float v = sm.a.m.ln.zb[r][seg * 12 + k];
            s1 += v; s2 += v * v;
        }
        sm.a.m.ln.ps1[r][seg] = s1; sm.a.m.ln.ps2[r][seg] = s2;
    }
    __syncthreads();
    if (t < 16) {
        float s1 = 0.f, s2 = 0.f;
        #pragma unroll
        for (int k = 0; k < 8; ++k) { s1 += sm.a.m.ln.ps1[t][k]; s2 += sm.a.m.ln.ps2[t][k]; }
        float mu  = s1 * (1.f / 96.f);
        float var = s2 * (1.f / 96.f) - mu * mu;
        sm.a.m.ln.stats[t][0] = mu;
        sm.a.m.ln.stats[t][1] = rsqrtf(var + 1e-5f);
    }
    __syncthreads();

    {   // write Z0 (raw) and Z (LN'd), layout [s][b][i], coalesced in i
        float gm = gamma[e], bt = beta[e];
        #pragma unroll
        for (int rr = 0; rr < 4; ++rr) {
            int r = q * 4 + rr;
            float z  = acc[rr];
            float mu = sm.a.m.ln.stats[r][0], rs = sm.a.m.ln.stats[r][1];
            size_t o = (size_t)(sb + r) * 768 + (size_t)b * 96 + e;
            Z0[o] = z;
            Z[o]  = (z - mu) * rs * gm + bt;
        }
    }
}

// ---------------------------------------------------------------------------
// kB: W-gen (Chebyshev over 8 s) + apply.  1024 blocks = 128 sg x 8 ih.
//   Thread owns 3 (i,j) pairs; per pair-g: 1 rcp + 3 cos serve 8 s values.
//   Phase B: ds_read_b128 on j-contiguous W/zs; Vt written 16B/lane via stage.
// ---------------------------------------------------------------------------
struct SmemB {
    float    zs[8][8][100];    // [s'][b][j] f32, pad 100 -> conflict-free (25600)
    uint16_t W[8][12][104];    // [s'][i'][j] bf16, row 208 B 16-aligned (19968)
    uint16_t stage[12][8][8];  // [i'][b][s'] (1536)
};

__global__ __launch_bounds__(384, 4) void kB(
    const float* __restrict__ P, const float* __restrict__ Z,
    const float* __restrict__ Z0, uint16_t* __restrict__ Vt)
{
    __shared__ SmemB sm;
    const int t  = threadIdx.x;
    const int sg = blockIdx.x >> 3;       // [0,128)
    const int ih = blockIdx.x & 7;        // [0,8)
    const int s0 = sg * 8;
    const int i0 = ih * 12;

    // ---- load zs: Z[(s0..s0+7)][b][j] = 24 KB contiguous ----
    #pragma unroll
    for (int k = 0; k < 4; ++k) {
        int c = t + 384 * k;              // f32x4 chunk id, [0,1536)
        int elem = c * 4;
        int sp = elem / 768, rem = elem - sp * 768;
        int bb = rem / 96,  j0 = rem - bb * 96;
        float4 v = *(const float4*)(Z + (size_t)s0 * 768 + elem);
        *(float4*)&sm.zs[sp][bb][j0] = v;
    }

    // ---- phase A: thread (j = t%96, iqb = t/96), 3 pairs ----
    {
        const int j   = t % 96;
        const int iqb = t / 96;
        const float sf = (float)s0;
        #pragma unroll 1
        for (int kk = 0; kk < 3; ++kk) {
            const int ip = kk * 4 + iqb;            // i' in [0,12)
            const int ig = i0 + ip;
            const float* Pp = P + ((size_t)ig * 96 + j) * 8;
            float4 pa = *(const float4*)(Pp);
            float4 pb = *(const float4*)(Pp + 4);
            float pv[8] = {pa.x, pa.y, pa.z, pa.w, pb.x, pb.y, pb.z, pb.w};
            float base = (float)((ig * 96 + j) * 8 + 2);   // exact (<2^23)
            float c[8], cp[8], tc[8];
            #pragma unroll
            for (int g = 0; g < 8; ++g) {
                float inv = __builtin_amdgcn_rcpf(base + (float)g);
                tc[g] = 2.0f * cosrev(inv);                 // inv <= 0.5 rev
                c[g]  = cosrev(__builtin_amdgcn_fractf(sf * inv));
                cp[g] = cosrev(__builtin_amdgcn_fractf((sf - 1.0f) * inv));
            }
            #pragma unroll
            for (int sp = 0; sp < 8; ++sp) {
                float w = 0.f;
                #pragma unroll
                for (int g = 0; g < 8; ++g) w = fmaf(pv[g], c[g], w);
                sm.W[sp][ip][j] = f2bf(w);
                #pragma unroll
                for (int g = 0; g < 8; ++g) {
                    float cn = fmaf(tc[g], c[g], -cp[g]);
                    cp[g] = c[g]; c[g] = cn;
                }
            }
        }
    }
    __syncthreads();

    // ---- phase B: thread (s2 = t/48, ip-pair, b); 2 i' x 96 j ----
    {
        const int s2  = t / 48;
        const int rem = t % 48;
        const int ipq = rem / 8;          // [0,6)
        const int bb  = rem % 8;
        const int ia  = ipq * 2, ib = ia + 1;
        float accA = 0.f, accB = 0.f;
        const uint16_t* w0 = &sm.W[s2][ia][0];
        const uint16_t* w1 = &sm.W[s2][ib][0];
        const float*    zz = &sm.zs[s2][bb][0];
        #pragma unroll 3
        for (int j0 = 0; j0 < 96; j0 += 8) {
            short8 wa = *(const short8*)(w0 + j0);
            short8 wb = *(const short8*)(w1 + j0);
            float4 z0 = *(const float4*)(zz + j0);
            float4 z1 = *(const float4*)(zz + j0 + 4);
            accA = fmaf(bf2f((uint16_t)wa[0]), z0.x, accA);
            accB = fmaf(bf2f((uint16_t)wb[0]), z0.x, accB);
            accA = fmaf(bf2f((uint16_t)wa[1]), z0.y, accA);
            accB = fmaf(bf2f((uint16_t)wb[1]), z0.y, accB);
            accA = fmaf(bf2f((uint16_t)wa[2]), z0.z, accA);
            accB = fmaf(bf2f((uint16_t)wb[2]), z0.z, accB);
            accA = fmaf(bf2f((uint16_t)wa[3]), z0.w, accA);
            accB = fmaf(bf2f((uint16_t)wb[3]), z0.w, accB);
            accA = fmaf(bf2f((uint16_t)wa[4]), z1.x, accA);
            accB = fmaf(bf2f((uint16_t)wb[4]), z1.x, accB);
            accA = fmaf(bf2f((uint16_t)wa[5]), z1.y, accA);
            accB = fmaf(bf2f((uint16_t)wb[5]), z1.y, accB);
            accA = fmaf(bf2f((uint16_t)wa[6]), z1.z, accA);
            accB = fmaf(bf2f((uint16_t)wb[6]), z1.z, accB);
            accA = fmaf(bf2f((uint16_t)wa[7]), z1.w, accA);
            accB = fmaf(bf2f((uint16_t)wb[7]), z1.w, accB);
        }
        // residual (contiguous f32x2) + stage
        float2 r2 = *(const float2*)(Z0 + (size_t)(s0 + s2) * 768 + bb * 96 + i0 + ia);
        sm.stage[ia][bb][s2] = f2bf(accA + r2.x);
        sm.stage[ib][bb][s2] = f2bf(accB + r2.y);
    }
    __syncthreads();

    // ---- Vt write: 16 B per (b,i) row, 96 lanes ----
    if (t < 96) {
        int ip = t >> 3, bb = t & 7;
        uint4 v = *(const uint4*)&sm.stage[ip][bb][0];
        *(uint4*)(Vt + ((size_t)bb * 96 + i0 + ip) * 1024 + s0) = v;
    }
}

// ---------------------------------------------------------------------------
// K3: out[b,t,i] = sum_s Lt[t][s]*Vt[b][i][s]
// Split-K x4 (4 waves) + i-half z-split: grid (64, 8, 2) = 1024 blocks,
// 256 thr -> 16 waves/CU.  Depth-2 pipelined loads, LDS combine.
// ---------------------------------------------------------------------------
__global__ __launch_bounds__(256, 4) void k3_mfma(
    const uint16_t* __restrict__ Lt, const uint16_t* __restrict__ Vt,
    float* __restrict__ out)
{
    __shared__ float racc[3][64][13];
    const int lane = threadIdx.x & 63;
    const int kw   = threadIdx.x >> 6;      // 0..3
    const int m    = lane & 15;
    const int quad = lane >> 4;
    const int t0   = blockIdx.x * 16;
    const int b    = blockIdx.y;
    const int ih   = blockIdx.z;            // i-half

    const uint16_t* Lp = Lt + (size_t)(t0 + m) * 1024 + kw * 256 + quad * 8;
    const uint16_t* Vp = Vt + ((size_t)b * 96 + ih * 48 + m) * 1024 + kw * 256 + quad * 8;

    f32x4 acc[3];
    #pragma unroll
    for (int ii = 0; ii < 3; ++ii) acc[ii] = (f32x4){0.f, 0.f, 0.f, 0.f};

    short8 a = *(const short8*)Lp;
    short8 bv[3];
    #pragma unroll
    for (int ii = 0; ii < 3; ++ii)
        bv[ii] = *(const short8*)(Vp + (size_t)ii * 16 * 1024);

    for (int kc = 0; kc < 7; ++kc) {
        short8 an = *(const short8*)(Lp + (kc + 1) * 32);
        short8 bn[3];
        #pragma unroll
        for (int ii = 0; ii < 3; ++ii)
            bn[ii] = *(const short8*)(Vp + (size_t)ii * 16 * 1024 + (kc + 1) * 32);
        #pragma unroll
        for (int ii = 0; ii < 3; ++ii)
            acc[ii] = __builtin_amdgcn_mfma_f32_16x16x32_bf16(a, bv[ii], acc[ii], 0, 0, 0);
        a = an;
        #pragma unroll
        for (int ii = 0; ii < 3; ++ii) bv[ii] = bn[ii];
    }
    #pragma unroll
    for (int ii = 0; ii < 3; ++ii)
        acc[ii] = __builtin_amdgcn_mfma_f32_16x16x32_bf16(a, bv[ii], acc[ii], 0, 0, 0);

    if (kw > 0) {
        #pragma unroll
        for (int ii = 0; ii < 3; ++ii)
            #pragma unroll
            for (int r = 0; r < 4; ++r)
                racc[kw - 1][lane][ii * 4 + r] = acc[ii][r];
    }
    __syncthreads();
    if (kw == 0) {
        float* po = out + (size_t)b * BSTRIDE;
        #pragma unroll
        for (int ii = 0; ii < 3; ++ii)
            #pragma unroll
            for (int r = 0; r < 4; ++r)
                po[(size_t)(t0 + quad * 4 + r) * 96 + ih * 48 + ii * 16 + m] =
                    acc[ii][r] + racc[0][lane][ii * 4 + r] +
                    racc[1][lane][ii * 4 + r] + racc[2][lane][ii * 4 + r];
    }
}

extern "C" void kernel_launch(void* const* d_in, const int* in_sizes, int n_in,
                              void* d_out, int out_size, void* d_ws, size_t ws_size,
                              hipStream_t stream)
{
    const float* x     = (const float*)d_in[0];
    const float* M     = (const float*)d_in[1];
    const float* P     = (const float*)d_in[2];
    const float* Lnk   = (const float*)d_in[3];
    const float* gamma = (const float*)d_in[4];
    const float* beta  = (const float*)d_in[5];
    float* out = (float*)d_out;

    uint8_t* ws = (uint8_t*)d_ws;
    uint16_t* Lt = (uint16_t*)ws;                 // 2,097,152 B
    uint16_t* Vt = (uint16_t*)(ws + 2097152);     // 1,572,864 B
    float*    Z0 = (float*)(ws + 3670016);        // 3,145,728 B
    float*    Z  = (float*)(ws + 6815744);        // 3,145,728 B

    kA<<<768, 384, 0, stream>>>(x, M, Lnk, gamma, beta, Z0, Z, Lt);
    kB<<<1024, 384, 0, stream>>>(P, Z, Z0, Vt);
    k3_mfma<<<dim3(64, 8, 2), 256, 0, stream>>>(Lt, Vt, out);
}